// Round 1
// baseline (1067.151 us; speedup 1.0000x reference)
//
#include <hip/hip_runtime.h>
#include <stdint.h>

namespace {
constexpr int  kN  = 10000;
constexpr int  kE  = 320000;
constexpr int  kHD = 32;
constexpr long kPOff = 10000;                      // p offset (floats) in d_out
constexpr long kHOff = 10000L + 100000000L;        // h_new offset
constexpr long kTOff = kHOff + 320000L;            // t offset
}

typedef float f32x4 __attribute__((ext_vector_type(4)));

// acc[j] += sum_k row[k] * W[k*32+j]  (32 inputs x 32 outputs, fully static)
__device__ __forceinline__ void fma_block32(const float* __restrict__ row,
                                            const float* __restrict__ W,
                                            float acc[32]) {
    const float4* r4 = reinterpret_cast<const float4*>(row);
#pragma unroll
    for (int q = 0; q < 8; ++q) {
        float4 v = r4[q];
        float in0 = v.x, in1 = v.y, in2 = v.z, in3 = v.w;
        const float* W0 = W + (q * 4 + 0) * 32;
        const float* W1 = W + (q * 4 + 1) * 32;
        const float* W2 = W + (q * 4 + 2) * 32;
        const float* W3 = W + (q * 4 + 3) * 32;
#pragma unroll
        for (int j = 0; j < 32; ++j) acc[j] = fmaf(in0, W0[j], acc[j]);
#pragma unroll
        for (int j = 0; j < 32; ++j) acc[j] = fmaf(in1, W1[j], acc[j]);
#pragma unroll
        for (int j = 0; j < 32; ++j) acc[j] = fmaf(in2, W2[j], acc[j]);
#pragma unroll
        for (int j = 0; j < 32; ++j) acc[j] = fmaf(in3, W3[j], acc[j]);
    }
}

// z = cat[x,h] @ W_enc + b_enc ; also init m = -inf and sum_h = 0
__global__ __launch_bounds__(256) void enc_kernel(
    const float* __restrict__ x, const float* __restrict__ h,
    const float* __restrict__ W_enc, const float* __restrict__ b_enc,
    float* __restrict__ z, float* __restrict__ m, float* __restrict__ sum_h)
{
    int i = blockIdx.x * 256 + threadIdx.x;
    if (blockIdx.x == 0 && threadIdx.x < kHD) sum_h[threadIdx.x] = 0.0f;
    if (i >= kN) return;
    float acc[32];
    float xi = x[i];
#pragma unroll
    for (int j = 0; j < 32; ++j) acc[j] = fmaf(xi, W_enc[j], b_enc[j]);
    fma_block32(h + (long)i * 32, W_enc + 32, acc);

    const float NEG_INF = __int_as_float(0xFF800000u);
    float4* zrow = reinterpret_cast<float4*>(z + (long)i * 32);
    float4* mrow = reinterpret_cast<float4*>(m + (long)i * 32);
#pragma unroll
    for (int q = 0; q < 8; ++q) {
        zrow[q] = make_float4(acc[q * 4 + 0], acc[q * 4 + 1], acc[q * 4 + 2], acc[q * 4 + 3]);
        mrow[q] = make_float4(NEG_INF, NEG_INF, NEG_INF, NEG_INF);
    }
}

// messages = cat[z[d], z[s], w] @ W_msg + b_msg ; scatter-max into m[d]
__global__ __launch_bounds__(256) void msg_kernel(
    const int* __restrict__ src, const int* __restrict__ dst,
    const float* __restrict__ w, const float* __restrict__ z,
    const float* __restrict__ W_msg, const float* __restrict__ b_msg,
    float* __restrict__ m)
{
    int e = blockIdx.x * 256 + threadIdx.x;
    if (e >= kE) return;
    int s = src[e], d = dst[e];
    float we = w[e];
    float acc[32];
#pragma unroll
    for (int j = 0; j < 32; ++j) acc[j] = fmaf(we, W_msg[64 * 32 + j], b_msg[j]);
    fma_block32(z + (long)d * 32, W_msg, acc);
    fma_block32(z + (long)s * 32, W_msg + 32 * 32, acc);

    float* mrow = m + (long)d * 32;
    // snapshot current values (stale reads are safe: m grows monotonically)
    float curv[32];
    const float4* c4 = reinterpret_cast<const float4*>(mrow);
#pragma unroll
    for (int q = 0; q < 8; ++q) {
        float4 v = c4[q];
        curv[q * 4 + 0] = v.x; curv[q * 4 + 1] = v.y;
        curv[q * 4 + 2] = v.z; curv[q * 4 + 3] = v.w;
    }
#pragma unroll
    for (int j = 0; j < 32; ++j) {
        float val = acc[j];
        if (val > curv[j]) {
            if (val >= 0.0f)
                atomicMax(reinterpret_cast<int*>(mrow + j), __float_as_int(val));
            else
                atomicMin(reinterpret_cast<unsigned int*>(mrow + j), __float_as_uint(val));
        }
    }
}

// h_new = cat[z,m0] @ W_upd + b_upd ; y = cat[z,h_new] @ W_dec + b_dec ; sum_h += h_new
__global__ __launch_bounds__(256) void upd_kernel(
    const float* __restrict__ z, const float* __restrict__ m,
    const float* __restrict__ W_upd, const float* __restrict__ b_upd,
    const float* __restrict__ W_dec, const float* __restrict__ b_dec,
    float* __restrict__ y_out, float* __restrict__ h_out,
    float* __restrict__ sum_h)
{
    int i = blockIdx.x * 256 + threadIdx.x;
    bool valid = i < kN;
    int ii = valid ? i : (kN - 1);

    float zr[32], mm[32];
    const float4* z4 = reinterpret_cast<const float4*>(z + (long)ii * 32);
    const float4* m4 = reinterpret_cast<const float4*>(m + (long)ii * 32);
#pragma unroll
    for (int q = 0; q < 8; ++q) {
        float4 v = z4[q];
        zr[q * 4 + 0] = v.x; zr[q * 4 + 1] = v.y; zr[q * 4 + 2] = v.z; zr[q * 4 + 3] = v.w;
        float4 u = m4[q];
        mm[q * 4 + 0] = u.x; mm[q * 4 + 1] = u.y; mm[q * 4 + 2] = u.z; mm[q * 4 + 3] = u.w;
    }
#pragma unroll
    for (int k = 0; k < 32; ++k)
        if (mm[k] == -INFINITY) mm[k] = 0.0f;

    float acc[32];
#pragma unroll
    for (int j = 0; j < 32; ++j) acc[j] = b_upd[j];
#pragma unroll
    for (int k = 0; k < 32; ++k) {
        const float* Wr = W_upd + k * 32;
#pragma unroll
        for (int j = 0; j < 32; ++j) acc[j] = fmaf(zr[k], Wr[j], acc[j]);
    }
#pragma unroll
    for (int k = 0; k < 32; ++k) {
        const float* Wr = W_upd + (32 + k) * 32;
#pragma unroll
        for (int j = 0; j < 32; ++j) acc[j] = fmaf(mm[k], Wr[j], acc[j]);
    }

    float yv = b_dec[0];
#pragma unroll
    for (int k = 0; k < 32; ++k) yv = fmaf(zr[k], W_dec[k], yv);
#pragma unroll
    for (int k = 0; k < 32; ++k) yv = fmaf(acc[k], W_dec[32 + k], yv);

    if (valid) {
        y_out[i] = yv;
        float4* hrow = reinterpret_cast<float4*>(h_out + (long)i * 32);
#pragma unroll
        for (int q = 0; q < 8; ++q)
            hrow[q] = make_float4(acc[q * 4 + 0], acc[q * 4 + 1], acc[q * 4 + 2], acc[q * 4 + 3]);
    }

    // per-wave reduction of h_new into sum_h
#pragma unroll
    for (int j = 0; j < 32; ++j) {
        float v = valid ? acc[j] : 0.0f;
#pragma unroll
        for (int off = 32; off; off >>= 1) v += __shfl_down(v, off, 64);
        if ((threadIdx.x & 63) == 0) atomicAdd(sum_h + j, v);
    }
}

__global__ void term_kernel(const float* __restrict__ sum_h,
                            const float* __restrict__ W_term,
                            const float* __restrict__ b_term,
                            float* __restrict__ t_out)
{
    int l = threadIdx.x;
    float v = (l < 32) ? (sum_h[l] * (1.0f / (float)kN)) * W_term[l] : 0.0f;
#pragma unroll
    for (int off = 32; off; off >>= 1) v += __shfl_down(v, off, 64);
    if (l == 0) t_out[0] = v + b_term[0];
}

__global__ __launch_bounds__(256) void fill_kernel(float* __restrict__ p)
{
    long idx = (long)blockIdx.x * 256 + threadIdx.x;
    long stride = (long)gridDim.x * 256;
    const long total4 = (long)kN * (long)kN / 4;   // 25,000,000
    f32x4 v = { -1e9f, -1e9f, -1e9f, -1e9f };
    f32x4* p4 = reinterpret_cast<f32x4*>(p);
    for (long i = idx; i < total4; i += stride)
        __builtin_nontemporal_store(v, p4 + i);
}

// edge_scores = cat[hn[d], hn[s], w] @ W_pred + b_pred ; p[d,s] = score
__global__ __launch_bounds__(256) void pred_kernel(
    const int* __restrict__ src, const int* __restrict__ dst,
    const float* __restrict__ w, const float* __restrict__ hn,
    const float* __restrict__ W_pred, const float* __restrict__ b_pred,
    float* __restrict__ p)
{
    int e = blockIdx.x * 256 + threadIdx.x;
    if (e >= kE) return;
    int s = src[e], d = dst[e];
    float acc = fmaf(w[e], W_pred[64], b_pred[0]);
    const float4* dr = reinterpret_cast<const float4*>(hn + (long)d * 32);
    const float4* sr = reinterpret_cast<const float4*>(hn + (long)s * 32);
#pragma unroll
    for (int q = 0; q < 8; ++q) {
        float4 a = dr[q];
        float4 b = sr[q];
        acc = fmaf(a.x, W_pred[q * 4 + 0], acc);
        acc = fmaf(a.y, W_pred[q * 4 + 1], acc);
        acc = fmaf(a.z, W_pred[q * 4 + 2], acc);
        acc = fmaf(a.w, W_pred[q * 4 + 3], acc);
        acc = fmaf(b.x, W_pred[32 + q * 4 + 0], acc);
        acc = fmaf(b.y, W_pred[32 + q * 4 + 1], acc);
        acc = fmaf(b.z, W_pred[32 + q * 4 + 2], acc);
        acc = fmaf(b.w, W_pred[32 + q * 4 + 3], acc);
    }
    p[(long)d * kN + s] = acc;
}

extern "C" void kernel_launch(void* const* d_in, const int* in_sizes, int n_in,
                              void* d_out, int out_size, void* d_ws, size_t ws_size,
                              hipStream_t stream)
{
    const int*   sources = (const int*)d_in[0];
    const int*   dests   = (const int*)d_in[1];
    const float* weights = (const float*)d_in[2];
    const float* x       = (const float*)d_in[3];
    const float* h       = (const float*)d_in[4];
    const float* W_enc   = (const float*)d_in[5];
    const float* b_enc   = (const float*)d_in[6];
    const float* W_msg   = (const float*)d_in[7];
    const float* b_msg   = (const float*)d_in[8];
    const float* W_upd   = (const float*)d_in[9];
    const float* b_upd   = (const float*)d_in[10];
    const float* W_dec   = (const float*)d_in[11];
    const float* b_dec   = (const float*)d_in[12];
    const float* W_term  = (const float*)d_in[13];
    const float* b_term  = (const float*)d_in[14];
    const float* W_pred  = (const float*)d_in[15];
    const float* b_pred  = (const float*)d_in[16];

    float* out   = (float*)d_out;
    float* z     = (float*)d_ws;                 // N*32 floats
    float* m     = z + (long)kN * kHD;           // N*32 floats
    float* sum_h = m + (long)kN * kHD;           // 32 floats

    float* y_out = out;
    float* p_out = out + kPOff;
    float* h_out = out + kHOff;
    float* t_out = out + kTOff;

    enc_kernel<<<(kN + 255) / 256, 256, 0, stream>>>(x, h, W_enc, b_enc, z, m, sum_h);
    fill_kernel<<<2048, 256, 0, stream>>>(p_out);
    msg_kernel<<<(kE + 255) / 256, 256, 0, stream>>>(sources, dests, weights, z, W_msg, b_msg, m);
    upd_kernel<<<(kN + 255) / 256, 256, 0, stream>>>(z, m, W_upd, b_upd, W_dec, b_dec,
                                                     y_out, h_out, sum_h);
    term_kernel<<<1, 64, 0, stream>>>(sum_h, W_term, b_term, t_out);
    pred_kernel<<<(kE + 255) / 256, 256, 0, stream>>>(sources, dests, weights, h_out,
                                                      W_pred, b_pred, p_out);
}

// Round 3
// 729.966 us; speedup vs baseline: 1.4619x; 1.4619x over previous
//
#include <hip/hip_runtime.h>
#include <stdint.h>

namespace {
constexpr int  kN  = 10000;
constexpr int  kE  = 320000;
constexpr long kPOff = 10000;                      // p offset (floats) in d_out
constexpr long kHOff = 10000L + 100000000L;        // h_new offset
constexpr long kTOff = kHOff + 320000L;            // t offset
}

typedef float f32x4 __attribute__((ext_vector_type(4)));

// acc[j] += sum_k row[k] * W[k*32+j]  (32 inputs x 32 outputs, fully static)
__device__ __forceinline__ void fma_block32(const float* __restrict__ row,
                                            const float* __restrict__ W,
                                            float acc[32]) {
    const float4* r4 = reinterpret_cast<const float4*>(row);
#pragma unroll
    for (int q = 0; q < 8; ++q) {
        float4 v = r4[q];
        float in0 = v.x, in1 = v.y, in2 = v.z, in3 = v.w;
        const float* W0 = W + (q * 4 + 0) * 32;
        const float* W1 = W + (q * 4 + 1) * 32;
        const float* W2 = W + (q * 4 + 2) * 32;
        const float* W3 = W + (q * 4 + 3) * 32;
#pragma unroll
        for (int j = 0; j < 32; ++j) acc[j] = fmaf(in0, W0[j], acc[j]);
#pragma unroll
        for (int j = 0; j < 32; ++j) acc[j] = fmaf(in1, W1[j], acc[j]);
#pragma unroll
        for (int j = 0; j < 32; ++j) acc[j] = fmaf(in2, W2[j], acc[j]);
#pragma unroll
        for (int j = 0; j < 32; ++j) acc[j] = fmaf(in3, W3[j], acc[j]);
    }
}

// z = cat[x,h] @ W_enc + b_enc ; zero deg/cursor/sum_h
__global__ __launch_bounds__(256) void enc_kernel(
    const float* __restrict__ x, const float* __restrict__ h,
    const float* __restrict__ W_enc, const float* __restrict__ b_enc,
    float* __restrict__ z, int* __restrict__ deg, int* __restrict__ cursor,
    float* __restrict__ sum_h)
{
    int i = blockIdx.x * 256 + threadIdx.x;
    if (i < 32) sum_h[i] = 0.0f;
    if (i < kN) { deg[i] = 0; cursor[i] = 0; }
    if (i >= kN) return;
    float acc[32];
    float xi = x[i];
#pragma unroll
    for (int j = 0; j < 32; ++j) acc[j] = fmaf(xi, W_enc[j], b_enc[j]);
    fma_block32(h + (long)i * 32, W_enc + 32, acc);

    float4* zrow = reinterpret_cast<float4*>(z + (long)i * 32);
#pragma unroll
    for (int q = 0; q < 8; ++q)
        zrow[q] = make_float4(acc[q * 4 + 0], acc[q * 4 + 1], acc[q * 4 + 2], acc[q * 4 + 3]);
}

__global__ __launch_bounds__(256) void hist_kernel(const int* __restrict__ dst,
                                                   int* __restrict__ deg)
{
    int e = blockIdx.x * 256 + threadIdx.x;
    if (e < kE) atomicAdd(&deg[dst[e]], 1);
}

// exclusive prefix sum of deg[10000] -> rowptr ; single block of 256 threads
__global__ __launch_bounds__(256) void scan_kernel(const int* __restrict__ deg,
                                                   int* __restrict__ rowptr)
{
    __shared__ int part[256];
    const int CH = 40;                  // 256*40 = 10240 >= kN
    int t = threadIdx.x;
    int vals[CH];
    int local = 0;
#pragma unroll
    for (int i = 0; i < CH; ++i) {
        int idx = t * CH + i;
        int v = (idx < kN) ? deg[idx] : 0;
        vals[i] = local;
        local += v;
    }
    part[t] = local;
    __syncthreads();
    for (int off = 1; off < 256; off <<= 1) {
        int v = (t >= off) ? part[t - off] : 0;
        __syncthreads();
        part[t] += v;
        __syncthreads();
    }
    int excl = part[t] - local;
#pragma unroll
    for (int i = 0; i < CH; ++i) {
        int idx = t * CH + i;
        if (idx < kN) rowptr[idx] = excl + vals[i];
    }
}

__global__ __launch_bounds__(256) void scatter_kernel(
    const int* __restrict__ dst, const int* __restrict__ rowptr,
    int* __restrict__ cursor, int* __restrict__ elist)
{
    int e = blockIdx.x * 256 + threadIdx.x;
    if (e >= kE) return;
    int d = dst[e];
    int pos = atomicAdd(&cursor[d], 1);
    elist[rowptr[d] + pos] = e;
}

// one wave per dest: m[d][j] = max over edges of (msg_j), -inf -> 0. No atomics.
__global__ __launch_bounds__(256) void gathermax_kernel(
    const int* __restrict__ src, const float* __restrict__ w,
    const float* __restrict__ z, const int* __restrict__ rowptr,
    const int* __restrict__ deg, const int* __restrict__ elist,
    const float* __restrict__ W_msg, const float* __restrict__ b_msg,
    float* __restrict__ m)
{
    int lane = threadIdx.x & 63;
    int wid  = threadIdx.x >> 6;
    int d = blockIdx.x * 4 + wid;
    if (d >= kN) return;
    int j = lane & 31;
    int half = lane >> 5;

    // resident column j of the z_src block of W_msg
    float Ws[32];
#pragma unroll
    for (int k = 0; k < 32; ++k) Ws[k] = W_msg[(32 + k) * 32 + j];
    float Ww = W_msg[64 * 32 + j];

    // partial_d[j] = b_msg[j] + sum_k z[d][k] * W_msg[k][j]  (same for all edges)
    float zd = z[(long)d * 32 + j];
    float partial = b_msg[j];
#pragma unroll
    for (int k = 0; k < 32; ++k)
        partial = fmaf(__shfl(zd, k, 32), W_msg[k * 32 + j], partial);

    float mx = -__builtin_inff();
    int base = rowptr[d], cnt = deg[d];
    for (int i = half; i < cnt; i += 2) {
        int e = elist[base + i];
        int s = src[e];
        float we = w[e];
        float zs = z[(long)s * 32 + j];
        float msg = fmaf(we, Ww, partial);
#pragma unroll
        for (int k = 0; k < 32; ++k)
            msg = fmaf(__shfl(zs, k, 32), Ws[k], msg);
        mx = fmaxf(mx, msg);
    }
    mx = fmaxf(mx, __shfl_xor(mx, 32, 64));
    if (half == 0)
        m[(long)d * 32 + j] = (mx == -__builtin_inff()) ? 0.0f : mx;
}

// h_new = cat[z,m] @ W_upd + b_upd ; y = cat[z,h_new] @ W_dec + b_dec ; sum_h += h_new
// streamed (no 96-float arrays, no spills)
__global__ __launch_bounds__(256) void upd_kernel(
    const float* __restrict__ z, const float* __restrict__ m,
    const float* __restrict__ W_upd, const float* __restrict__ b_upd,
    const float* __restrict__ W_dec, const float* __restrict__ b_dec,
    float* __restrict__ y_out, float* __restrict__ h_out,
    float* __restrict__ sum_h)
{
    int i = blockIdx.x * 256 + threadIdx.x;
    bool valid = i < kN;
    int ii = valid ? i : (kN - 1);

    float acc[32];
#pragma unroll
    for (int j = 0; j < 32; ++j) acc[j] = b_upd[j];
    float yv = b_dec[0];

    const float4* z4 = reinterpret_cast<const float4*>(z + (long)ii * 32);
#pragma unroll
    for (int q = 0; q < 8; ++q) {
        float4 v = z4[q];
        float in0 = v.x, in1 = v.y, in2 = v.z, in3 = v.w;
        int k = q * 4;
        yv = fmaf(in0, W_dec[k + 0], yv);
        yv = fmaf(in1, W_dec[k + 1], yv);
        yv = fmaf(in2, W_dec[k + 2], yv);
        yv = fmaf(in3, W_dec[k + 3], yv);
        const float* W0 = W_upd + (k + 0) * 32;
        const float* W1 = W_upd + (k + 1) * 32;
        const float* W2 = W_upd + (k + 2) * 32;
        const float* W3 = W_upd + (k + 3) * 32;
#pragma unroll
        for (int j = 0; j < 32; ++j) acc[j] = fmaf(in0, W0[j], acc[j]);
#pragma unroll
        for (int j = 0; j < 32; ++j) acc[j] = fmaf(in1, W1[j], acc[j]);
#pragma unroll
        for (int j = 0; j < 32; ++j) acc[j] = fmaf(in2, W2[j], acc[j]);
#pragma unroll
        for (int j = 0; j < 32; ++j) acc[j] = fmaf(in3, W3[j], acc[j]);
    }
    // m already has -inf replaced by 0 in gathermax
    fma_block32(m + (long)ii * 32, W_upd + 32 * 32, acc);

#pragma unroll
    for (int k = 0; k < 32; ++k) yv = fmaf(acc[k], W_dec[32 + k], yv);

    if (valid) {
        y_out[i] = yv;
        float4* hrow = reinterpret_cast<float4*>(h_out + (long)i * 32);
#pragma unroll
        for (int q = 0; q < 8; ++q)
            hrow[q] = make_float4(acc[q * 4 + 0], acc[q * 4 + 1], acc[q * 4 + 2], acc[q * 4 + 3]);
    }

#pragma unroll
    for (int j = 0; j < 32; ++j) {
        float v = valid ? acc[j] : 0.0f;
#pragma unroll
        for (int off = 32; off; off >>= 1) v += __shfl_down(v, off, 64);
        if ((threadIdx.x & 63) == 0) atomicAdd(sum_h + j, v);
    }
}

__global__ void term_kernel(const float* __restrict__ sum_h,
                            const float* __restrict__ W_term,
                            const float* __restrict__ b_term,
                            float* __restrict__ t_out)
{
    int l = threadIdx.x;
    float v = (l < 32) ? (sum_h[l] * (1.0f / (float)kN)) * W_term[l] : 0.0f;
#pragma unroll
    for (int off = 32; off; off >>= 1) v += __shfl_down(v, off, 64);
    if (l == 0) t_out[0] = v + b_term[0];
}

__global__ __launch_bounds__(256) void fill_kernel(float* __restrict__ p)
{
    long idx = (long)blockIdx.x * 256 + threadIdx.x;
    long stride = (long)gridDim.x * 256;
    const long total4 = (long)kN * (long)kN / 4;   // 25,000,000
    f32x4 v = { -1e9f, -1e9f, -1e9f, -1e9f };
    f32x4* p4 = reinterpret_cast<f32x4*>(p);
    for (long i = idx; i < total4; i += stride)
        __builtin_nontemporal_store(v, p4 + i);
}

// edge_scores = cat[hn[d], hn[s], w] @ W_pred + b_pred ; p[d,s] = score
__global__ __launch_bounds__(256) void pred_kernel(
    const int* __restrict__ src, const int* __restrict__ dst,
    const float* __restrict__ w, const float* __restrict__ hn,
    const float* __restrict__ W_pred, const float* __restrict__ b_pred,
    float* __restrict__ p)
{
    int e = blockIdx.x * 256 + threadIdx.x;
    if (e >= kE) return;
    int s = src[e], d = dst[e];
    float acc = fmaf(w[e], W_pred[64], b_pred[0]);
    const float4* dr = reinterpret_cast<const float4*>(hn + (long)d * 32);
    const float4* sr = reinterpret_cast<const float4*>(hn + (long)s * 32);
#pragma unroll
    for (int q = 0; q < 8; ++q) {
        float4 a = dr[q];
        float4 b = sr[q];
        acc = fmaf(a.x, W_pred[q * 4 + 0], acc);
        acc = fmaf(a.y, W_pred[q * 4 + 1], acc);
        acc = fmaf(a.z, W_pred[q * 4 + 2], acc);
        acc = fmaf(a.w, W_pred[q * 4 + 3], acc);
        acc = fmaf(b.x, W_pred[32 + q * 4 + 0], acc);
        acc = fmaf(b.y, W_pred[32 + q * 4 + 1], acc);
        acc = fmaf(b.z, W_pred[32 + q * 4 + 2], acc);
        acc = fmaf(b.w, W_pred[32 + q * 4 + 3], acc);
    }
    p[(long)d * kN + s] = acc;
}

extern "C" void kernel_launch(void* const* d_in, const int* in_sizes, int n_in,
                              void* d_out, int out_size, void* d_ws, size_t ws_size,
                              hipStream_t stream)
{
    const int*   sources = (const int*)d_in[0];
    const int*   dests   = (const int*)d_in[1];
    const float* weights = (const float*)d_in[2];
    const float* x       = (const float*)d_in[3];
    const float* h       = (const float*)d_in[4];
    const float* W_enc   = (const float*)d_in[5];
    const float* b_enc   = (const float*)d_in[6];
    const float* W_msg   = (const float*)d_in[7];
    const float* b_msg   = (const float*)d_in[8];
    const float* W_upd   = (const float*)d_in[9];
    const float* b_upd   = (const float*)d_in[10];
    const float* W_dec   = (const float*)d_in[11];
    const float* b_dec   = (const float*)d_in[12];
    const float* W_term  = (const float*)d_in[13];
    const float* b_term  = (const float*)d_in[14];
    const float* W_pred  = (const float*)d_in[15];
    const float* b_pred  = (const float*)d_in[16];

    float* out   = (float*)d_out;
    float* y_out = out;
    float* p_out = out + kPOff;
    float* h_out = out + kHOff;
    float* t_out = out + kTOff;

    // workspace layout
    float* z      = (float*)d_ws;                    // N*32 f32
    float* m      = z + (long)kN * 32;               // N*32 f32
    float* sum_h  = m + (long)kN * 32;               // 32 f32
    int*   deg    = (int*)(sum_h + 32);              // N i32
    int*   rowptr = deg + kN;                        // N i32
    int*   cursor = rowptr + kN;                     // N i32
    // edge list borrows the p output region (p gets filled AFTER gathermax)
    int*   elist  = (int*)p_out;                     // E i32

    enc_kernel<<<(kN + 255) / 256, 256, 0, stream>>>(x, h, W_enc, b_enc, z, deg, cursor, sum_h);
    hist_kernel<<<(kE + 255) / 256, 256, 0, stream>>>(dests, deg);
    scan_kernel<<<1, 256, 0, stream>>>(deg, rowptr);
    scatter_kernel<<<(kE + 255) / 256, 256, 0, stream>>>(dests, rowptr, cursor, elist);
    gathermax_kernel<<<(kN + 3) / 4, 256, 0, stream>>>(sources, weights, z, rowptr, deg,
                                                       elist, W_msg, b_msg, m);
    upd_kernel<<<(kN + 255) / 256, 256, 0, stream>>>(z, m, W_upd, b_upd, W_dec, b_dec,
                                                     y_out, h_out, sum_h);
    term_kernel<<<1, 64, 0, stream>>>(sum_h, W_term, b_term, t_out);
    fill_kernel<<<4096, 256, 0, stream>>>(p_out);
    pred_kernel<<<(kE + 255) / 256, 256, 0, stream>>>(sources, dests, weights, h_out,
                                                      W_pred, b_pred, p_out);
}

// Round 4
// 557.360 us; speedup vs baseline: 1.9147x; 1.3097x over previous
//
#include <hip/hip_runtime.h>
#include <stdint.h>

namespace {
constexpr int  kN  = 10000;
constexpr int  kE  = 320000;
constexpr long kPOff = 10000;                      // p offset (floats) in d_out
constexpr long kHOff = 10000L + 100000000L;        // h_new offset
constexpr long kTOff = kHOff + 320000L;            // t offset
}

typedef float f32x4 __attribute__((ext_vector_type(4)));

__device__ __forceinline__ float shfl32(float v, int k) { return __shfl(v, k, 32); }

// Per-node precompute: z = cat[x,h]@W_enc+b_enc ; zwd = z@W_msg[0:32]+b_msg ;
// zws = z@W_msg[32:64] ; m = -inf.  One node per half-wave, lane j = channel j.
__global__ __launch_bounds__(256) void encz_kernel(
    const float* __restrict__ x, const float* __restrict__ h,
    const float* __restrict__ W_enc, const float* __restrict__ b_enc,
    const float* __restrict__ W_msg, const float* __restrict__ b_msg,
    float* __restrict__ z, float* __restrict__ zwd, float* __restrict__ zws,
    float* __restrict__ m)
{
    int lane = threadIdx.x & 63;
    int wid  = threadIdx.x >> 6;
    int half = lane >> 5;
    int j    = lane & 31;
    int i = blockIdx.x * 8 + wid * 2 + half;
    if (i >= kN) return;

    float hj = h[(long)i * 32 + j];
    float xi = x[i];
    float zj = fmaf(xi, W_enc[j], b_enc[j]);
#pragma unroll
    for (int k = 0; k < 32; ++k)
        zj = fmaf(shfl32(hj, k), W_enc[(1 + k) * 32 + j], zj);

    z[(long)i * 32 + j] = zj;
    m[(long)i * 32 + j] = -__builtin_inff();

    float dv = b_msg[j], sv = 0.0f;
#pragma unroll
    for (int k = 0; k < 32; ++k) {
        float zk = shfl32(zj, k);
        dv = fmaf(zk, W_msg[k * 32 + j], dv);
        sv = fmaf(zk, W_msg[(32 + k) * 32 + j], sv);
    }
    zwd[(long)i * 32 + j] = dv;
    zws[(long)i * 32 + j] = sv;
}

// Per-edge: msg_j = zwd[d][j] + zws[s][j] + w_e*Ww_j ; atomic scatter-max into m[d].
// One edge per half-wave; grid-stride over edge pairs.
__global__ __launch_bounds__(256) void msgmax_kernel(
    const int* __restrict__ src, const int* __restrict__ dst,
    const float* __restrict__ w, const float* __restrict__ zwd,
    const float* __restrict__ zws, const float* __restrict__ W_msg,
    float* __restrict__ m)
{
    int lane = threadIdx.x & 63;
    int wid  = threadIdx.x >> 6;
    int half = lane >> 5;
    int j    = lane & 31;
    float Ww = W_msg[64 * 32 + j];
    int gw = blockIdx.x * 4 + wid;
    int nw = gridDim.x * 4;
    for (int ep = gw; ep < kE / 2; ep += nw) {
        int e = ep * 2 + half;
        int d = dst[e], s = src[e];
        float val = fmaf(w[e], Ww, zwd[(long)d * 32 + j] + zws[(long)s * 32 + j]);
        float* addr = m + (long)d * 32 + j;
        if (val >= 0.0f)
            atomicMax(reinterpret_cast<int*>(addr), __float_as_int(val));
        else
            atomicMin(reinterpret_cast<unsigned int*>(addr), __float_as_uint(val));
    }
}

// h_new = cat[z,m0]@W_upd+b_upd ; y = cat[z,h_new]@W_dec+b_dec ;
// a[i] = h_new·W_pred[0:32] ; b[i] = h_new·W_pred[32:64] ; per-wave h_new partials.
__global__ __launch_bounds__(256) void updn_kernel(
    const float* __restrict__ z, const float* __restrict__ m,
    const float* __restrict__ W_upd, const float* __restrict__ b_upd,
    const float* __restrict__ W_dec, const float* __restrict__ b_dec,
    const float* __restrict__ W_pred,
    float* __restrict__ y_out, float* __restrict__ h_out,
    float* __restrict__ a_out, float* __restrict__ b_out,
    float* __restrict__ partials)
{
    int i = blockIdx.x * 256 + threadIdx.x;
    bool valid = i < kN;
    int ii = valid ? i : (kN - 1);

    float acc[32];
#pragma unroll
    for (int jj = 0; jj < 32; ++jj) acc[jj] = b_upd[jj];
    float yv = b_dec[0];

    const float4* z4 = reinterpret_cast<const float4*>(z + (long)ii * 32);
#pragma unroll
    for (int q = 0; q < 8; ++q) {
        float4 v = z4[q];
        float in0 = v.x, in1 = v.y, in2 = v.z, in3 = v.w;
        int k = q * 4;
        yv = fmaf(in0, W_dec[k + 0], yv);
        yv = fmaf(in1, W_dec[k + 1], yv);
        yv = fmaf(in2, W_dec[k + 2], yv);
        yv = fmaf(in3, W_dec[k + 3], yv);
        const float* W0 = W_upd + (k + 0) * 32;
        const float* W1 = W_upd + (k + 1) * 32;
        const float* W2 = W_upd + (k + 2) * 32;
        const float* W3 = W_upd + (k + 3) * 32;
#pragma unroll
        for (int jj = 0; jj < 32; ++jj) acc[jj] = fmaf(in0, W0[jj], acc[jj]);
#pragma unroll
        for (int jj = 0; jj < 32; ++jj) acc[jj] = fmaf(in1, W1[jj], acc[jj]);
#pragma unroll
        for (int jj = 0; jj < 32; ++jj) acc[jj] = fmaf(in2, W2[jj], acc[jj]);
#pragma unroll
        for (int jj = 0; jj < 32; ++jj) acc[jj] = fmaf(in3, W3[jj], acc[jj]);
    }

    const float NEG_INF = -__builtin_inff();
    const float4* m4 = reinterpret_cast<const float4*>(m + (long)ii * 32);
#pragma unroll
    for (int q = 0; q < 8; ++q) {
        float4 v = m4[q];
        float in0 = (v.x == NEG_INF) ? 0.0f : v.x;
        float in1 = (v.y == NEG_INF) ? 0.0f : v.y;
        float in2 = (v.z == NEG_INF) ? 0.0f : v.z;
        float in3 = (v.w == NEG_INF) ? 0.0f : v.w;
        int k = 32 + q * 4;
        const float* W0 = W_upd + (k + 0) * 32;
        const float* W1 = W_upd + (k + 1) * 32;
        const float* W2 = W_upd + (k + 2) * 32;
        const float* W3 = W_upd + (k + 3) * 32;
#pragma unroll
        for (int jj = 0; jj < 32; ++jj) acc[jj] = fmaf(in0, W0[jj], acc[jj]);
#pragma unroll
        for (int jj = 0; jj < 32; ++jj) acc[jj] = fmaf(in1, W1[jj], acc[jj]);
#pragma unroll
        for (int jj = 0; jj < 32; ++jj) acc[jj] = fmaf(in2, W2[jj], acc[jj]);
#pragma unroll
        for (int jj = 0; jj < 32; ++jj) acc[jj] = fmaf(in3, W3[jj], acc[jj]);
    }

    float av = 0.0f, bv = 0.0f;
#pragma unroll
    for (int k = 0; k < 32; ++k) {
        yv = fmaf(acc[k], W_dec[32 + k], yv);
        av = fmaf(acc[k], W_pred[k], av);
        bv = fmaf(acc[k], W_pred[32 + k], bv);
    }

    if (valid) {
        y_out[i] = yv;
        a_out[i] = av;
        b_out[i] = bv;
        float4* hrow = reinterpret_cast<float4*>(h_out + (long)i * 32);
#pragma unroll
        for (int q = 0; q < 8; ++q)
            hrow[q] = make_float4(acc[q * 4 + 0], acc[q * 4 + 1], acc[q * 4 + 2], acc[q * 4 + 3]);
    }

    // per-wave partial sums of h_new -> global (no atomics)
    int wslot = blockIdx.x * 4 + ((threadIdx.x >> 6) & 3);
#pragma unroll
    for (int jj = 0; jj < 32; ++jj) {
        float v = valid ? acc[jj] : 0.0f;
#pragma unroll
        for (int off = 32; off; off >>= 1) v += __shfl_down(v, off, 64);
        if ((threadIdx.x & 63) == 0) partials[(long)wslot * 32 + jj] = v;
    }
}

// t = (mean(h_new) @ W_term + b_term) ; one wave reduces 160x32 partials
__global__ void term_kernel(const float* __restrict__ partials,
                            const float* __restrict__ W_term,
                            const float* __restrict__ b_term,
                            float* __restrict__ t_out)
{
    int l = threadIdx.x;
    float s = 0.0f;
    if (l < 32) {
        for (int r = 0; r < 160; ++r) s += partials[(long)r * 32 + l];
        s = (s * (1.0f / (float)kN)) * W_term[l];
    }
#pragma unroll
    for (int off = 32; off; off >>= 1) s += __shfl_down(s, off, 64);
    if (l == 0) t_out[0] = s + b_term[0];
}

__global__ __launch_bounds__(256) void fill_kernel(float* __restrict__ p)
{
    long idx = (long)blockIdx.x * 256 + threadIdx.x;
    long stride = (long)gridDim.x * 256;
    const long total4 = (long)kN * (long)kN / 4;   // 25,000,000
    f32x4 v = { -1e9f, -1e9f, -1e9f, -1e9f };
    f32x4* p4 = reinterpret_cast<f32x4*>(p);
    for (long i = idx; i < total4; i += stride)
        p4[i] = v;                                  // plain stores (match rocclr fill BW)
}

// p[d,s] = a[d] + b[s] + w_e*W_pred[64] + b_pred
__global__ __launch_bounds__(256) void predl_kernel(
    const int* __restrict__ src, const int* __restrict__ dst,
    const float* __restrict__ w, const float* __restrict__ a,
    const float* __restrict__ b, const float* __restrict__ W_pred,
    const float* __restrict__ b_pred, float* __restrict__ p)
{
    int e = blockIdx.x * 256 + threadIdx.x;
    if (e >= kE) return;
    int d = dst[e], s = src[e];
    float score = a[d] + b[s] + fmaf(w[e], W_pred[64], b_pred[0]);
    p[(long)d * kN + s] = score;
}

extern "C" void kernel_launch(void* const* d_in, const int* in_sizes, int n_in,
                              void* d_out, int out_size, void* d_ws, size_t ws_size,
                              hipStream_t stream)
{
    const int*   sources = (const int*)d_in[0];
    const int*   dests   = (const int*)d_in[1];
    const float* weights = (const float*)d_in[2];
    const float* x       = (const float*)d_in[3];
    const float* h       = (const float*)d_in[4];
    const float* W_enc   = (const float*)d_in[5];
    const float* b_enc   = (const float*)d_in[6];
    const float* W_msg   = (const float*)d_in[7];
    const float* b_msg   = (const float*)d_in[8];
    const float* W_upd   = (const float*)d_in[9];
    const float* b_upd   = (const float*)d_in[10];
    const float* W_dec   = (const float*)d_in[11];
    const float* b_dec   = (const float*)d_in[12];
    const float* W_term  = (const float*)d_in[13];
    const float* b_term  = (const float*)d_in[14];
    const float* W_pred  = (const float*)d_in[15];
    const float* b_pred  = (const float*)d_in[16];

    float* out   = (float*)d_out;
    float* y_out = out;
    float* p_out = out + kPOff;
    float* h_out = out + kHOff;
    float* t_out = out + kTOff;

    // workspace layout (all f32)
    float* z        = (float*)d_ws;                  // N*32
    float* m        = z   + (long)kN * 32;           // N*32
    float* zwd      = m   + (long)kN * 32;           // N*32
    float* zws      = zwd + (long)kN * 32;           // N*32
    float* a_ws     = zws + (long)kN * 32;           // N
    float* b_ws     = a_ws + kN;                     // N
    float* partials = b_ws + kN;                     // 160*32

    encz_kernel<<<(kN + 7) / 8, 256, 0, stream>>>(x, h, W_enc, b_enc, W_msg, b_msg,
                                                  z, zwd, zws, m);
    msgmax_kernel<<<10000, 256, 0, stream>>>(sources, dests, weights, zwd, zws, W_msg, m);
    updn_kernel<<<(kN + 255) / 256, 256, 0, stream>>>(z, m, W_upd, b_upd, W_dec, b_dec,
                                                      W_pred, y_out, h_out, a_ws, b_ws,
                                                      partials);
    term_kernel<<<1, 64, 0, stream>>>(partials, W_term, b_term, t_out);
    fill_kernel<<<8192, 256, 0, stream>>>(p_out);
    predl_kernel<<<(kE + 255) / 256, 256, 0, stream>>>(sources, dests, weights, a_ws, b_ws,
                                                       W_pred, b_pred, p_out);
}